// Round 1
// 266.042 us; speedup vs baseline: 1.0079x; 1.0079x over previous
//
#include <hip/hip_runtime.h>
#include <stdint.h>

#define BB 512
#define TT 1000
#define CC 64
#define HH 128
#define TDA_F 150
#define NCLS 4
#define EPSV 1e-5f
#define NSEG 8
#define SEGLEN 125   // TT / NSEG
#define WARM 51      // uncounted warm-up; SEGLEN+WARM = 176 = 11 tiles of 16

typedef _Float16 half8 __attribute__((ext_vector_type(8)));
typedef float floatx4 __attribute__((ext_vector_type(4)));

// Split 8 fp32 values into fp16 hi + lo halves (hi = RTN cvt, lo = residual).
// (hi+lo) carries ~22 mantissa bits; 3-product MFMA error ~2^-21 relative.
__device__ __forceinline__ void split8(const float* v, half8& hi, half8& lo) {
#pragma unroll
  for (int i = 0; i < 8; ++i) {
    _Float16 h = (_Float16)v[i];
    hi[i] = h;
    lo[i] = (_Float16)(v[i] - (float)h);
  }
}

// ---------------------------------------------------------------------------
// Fused current-GEMM (split-fp16 MFMA) + LIF scan. Grid: 512 b x 8 seg,
// single-wave blocks (64 thr). Per 16-step tile: currents[16t x 128h] =
// kin_tile @ Wfc^T + b via mfma_f32_16x16x32_f16 (3-product split).
//
// R5 change: SOFTWARE PIPELINE. Tile k's split+MFMA is interleaved (by the
// scheduler, single basic block) with tile k-1's serial LIF chain, through
// TWO statically distinct LDS buffers curA/curB (static arrays so LLVM alias
// analysis can hoist LIF ds_reads of one buffer past ds_writes of the other;
// a runtime-indexed cur[2][..] would pessimize to program order). Main loop
// unrolled x2 so buffer roles are compile-time. Numerics are bit-identical
// to R4 (same FMA order). LDS 2x8448=16.9KB: LDS cap 9 blk/CU > reg cap
// 8 blk/CU (2 waves/SIMD at ~248 unified VGPR+AGPR) -> residency unchanged.
// Counters R4: MfmaUtil 17.7 / VALUBusy 29.6 -> both pipes mostly idle from
// in-wave phase serialization; this overlaps the two phases.
// ---------------------------------------------------------------------------

#define PITCH (16 * CC)

// Compute one 16t x 128h tile into LDS buffer CW. Consumes prefetch regs
// p0..p3 (copied to c), advances ab by `adv`, re-issues prefetch loads.
#define TILE_COMPUTE(CW)                                                      \
  {                                                                           \
    float4 c0 = p0, c1 = p1, c2 = p2, c3 = p3;                                \
    ab += adv;                                                                \
    p0 = *(const float4*)(ab);                                                \
    p1 = *(const float4*)(ab + 4);                                            \
    p2 = *(const float4*)(ab + 32);                                           \
    p3 = *(const float4*)(ab + 36);                                           \
    float av0[8] = {c0.x, c0.y, c0.z, c0.w, c1.x, c1.y, c1.z, c1.w};          \
    float av1[8] = {c2.x, c2.y, c2.z, c2.w, c3.x, c3.y, c3.z, c3.w};          \
    half8 ah0, al0, ah1, al1;                                                 \
    split8(av0, ah0, al0);                                                    \
    split8(av1, ah1, al1);                                                    \
    _Pragma("unroll")                                                         \
    for (int ht = 0; ht < 8; ++ht) {                                          \
      floatx4 acc = {bv[ht], bv[ht], bv[ht], bv[ht]};                         \
      acc = __builtin_amdgcn_mfma_f32_16x16x32_f16(al0, bh[ht][0], acc, 0, 0, 0); \
      acc = __builtin_amdgcn_mfma_f32_16x16x32_f16(ah0, bl[ht][0], acc, 0, 0, 0); \
      acc = __builtin_amdgcn_mfma_f32_16x16x32_f16(ah0, bh[ht][0], acc, 0, 0, 0); \
      acc = __builtin_amdgcn_mfma_f32_16x16x32_f16(al1, bh[ht][1], acc, 0, 0, 0); \
      acc = __builtin_amdgcn_mfma_f32_16x16x32_f16(ah1, bl[ht][1], acc, 0, 0, 0); \
      acc = __builtin_amdgcn_mfma_f32_16x16x32_f16(ah1, bh[ht][1], acc, 0, 0, 0); \
      _Pragma("unroll")                                                       \
      for (int r = 0; r < 4; ++r) CW[q * 4 + r][ht * 16 + m] = acc[r];        \
    }                                                                         \
  }

// Serial LIF over the 16 steps of the tile whose currents sit in CR.
// Lane owns h = lane and h = lane+64. tbase = absolute t of row 0.
#define LIF_TILE(CR, tbase)                                                   \
  {                                                                           \
    const int tb_ = (tbase);                                                  \
    _Pragma("unroll")                                                         \
    for (int s = 0; s < 16; ++s) {                                            \
      const float cu0 = CR[s][lane];                                          \
      const float cu1 = CR[s][lane + 64];                                     \
      const int t = tb_ + s;                                                  \
      const bool act = (t >= lo) && (t < hi); /* wave-uniform */              \
      mem0 = fmaf(0.9f, mem0, cu0);                                           \
      mem1 = fmaf(0.9f, mem1, cu1);                                           \
      const bool s0 = (mem0 >= 1.0f);                                         \
      const bool s1 = (mem1 >= 1.0f);                                         \
      cnt0 += (act && s0) ? 1.0f : 0.0f;                                      \
      cnt1 += (act && s1) ? 1.0f : 0.0f;                                      \
      mem0 = s0 ? 0.0f : mem0;                                                \
      mem1 = s1 ? 0.0f : mem1;                                                \
    }                                                                         \
  }

__global__ __launch_bounds__(64, 2) void snn_scan(
    const float* __restrict__ kin, const float* __restrict__ Wfc,
    const float* __restrict__ bfc, float* __restrict__ part)
{
  const int lane = threadIdx.x;
  const int q = lane >> 4;      // quad 0..3
  const int m = lane & 15;      // row-in-tile / col-in-tile index
  const int b = blockIdx.x >> 3;
  const int seg = blockIdx.x & 7;

  const int t0 = (seg == 0) ? 0 : SEGLEN * seg - WARM;
  const int ntiles = (seg == 0) ? 8 : 11;   // 128 or 176 steps
  const int lo = SEGLEN * seg;
  const int hi = lo + SEGLEN;

  // B fragments: B[n=m][k=q*8+j], n = ht*16+m over 8 h-tiles, k split in two
  // 32-wide halves. 32 half8 frags (128 regs) -- AGPR-demotable for free.
  half8 bh[8][2], bl[8][2];
  float bv[8];
#pragma unroll
  for (int ht = 0; ht < 8; ++ht) {
    bv[ht] = bfc[ht * 16 + m];
#pragma unroll
    for (int kh = 0; kh < 2; ++kh) {
      const float* wp = Wfc + (ht * 16 + m) * CC + kh * 32 + q * 8;
      float av[8];
      float4 w0 = *(const float4*)(wp);
      float4 w1 = *(const float4*)(wp + 4);
      av[0] = w0.x; av[1] = w0.y; av[2] = w0.z; av[3] = w0.w;
      av[4] = w1.x; av[5] = w1.y; av[6] = w1.z; av[7] = w1.w;
      split8(av, bh[ht][kh], bl[ht][kh]);
    }
  }

  // Double-buffered current tiles. Pad 132 -> <=2-way banks everywhere.
  // STATIC arrays (not cur[2][..]) so the scheduler can interleave reads of
  // one with writes of the other.
  __shared__ float curA[16][132];
  __shared__ float curB[16][132];

  // A pointer: lane reads rows t = t_base + m, cols q*8.. (two k-halves).
  const float* ab = kin + ((size_t)b * TT + (t0 + m)) * CC + q * 8;

  float4 p0 = *(const float4*)(ab);
  float4 p1 = *(const float4*)(ab + 4);
  float4 p2 = *(const float4*)(ab + 32);
  float4 p3 = *(const float4*)(ab + 36);

  float mem0 = 0.f, mem1 = 0.f, cnt0 = 0.f, cnt1 = 0.f;
  int adv;

  // Prologue: tile 0 -> curA (ntiles >= 8, so tile 1 always exists).
  adv = PITCH;
  TILE_COMPUTE(curA);

  // Steady state: compute tile k while LIF-ing tile k-1 (other buffer).
  int tile = 1;
  for (; tile + 1 < ntiles; tile += 2) {
    adv = PITCH;                              // tile+1 < ntiles in loop
    TILE_COMPUTE(curB);                       // tile (odd) -> B
    LIF_TILE(curA, t0 + (tile - 1) * 16);     // tile-1 (even) from A
    adv = (tile + 2 < ntiles) ? PITCH : 0;
    TILE_COMPUTE(curA);                       // tile+1 (even) -> A
    LIF_TILE(curB, t0 + tile * 16);           // tile (odd) from B
  }
  if (tile < ntiles) {                        // leftover (ntiles even, seg 0)
    adv = 0;
    TILE_COMPUTE(curB);                       // last tile (odd) -> B
    LIF_TILE(curA, t0 + (tile - 1) * 16);
    LIF_TILE(curB, t0 + tile * 16);
  } else {                                    // ntiles odd (11): last was even -> A
    LIF_TILE(curA, t0 + (ntiles - 1) * 16);
  }

  float* p = part + ((size_t)(seg * BB + b)) * HH;
  p[lane] = cnt0;
  p[lane + 64] = cnt1;
}

// ---------------------------------------------------------------------------
// Fused head: partial-count reduce + counts output + tda_net
// (150->64 relu ->64 relu) + fc1 (192->128). No atomics.
// ---------------------------------------------------------------------------
__global__ __launch_bounds__(HH) void fused_head(
    const float* __restrict__ part, const float* __restrict__ tda,
    const float* __restrict__ W1, const float* __restrict__ b1,
    const float* __restrict__ W2, const float* __restrict__ b2,
    const float* __restrict__ Wc1, const float* __restrict__ bc1,
    float* __restrict__ counts_out, float* __restrict__ hbuf)
{
  const int b = blockIdx.x, j = threadIdx.x;
  __shared__ float x[TDA_F];
  __shared__ float h1[64];
  __shared__ float f[HH + 64];

  float c = 0.0f;
#pragma unroll
  for (int s = 0; s < NSEG; ++s) c += part[((size_t)(s * BB + b)) * HH + j];
  counts_out[b * HH + j] = c;
  f[j] = c * (1.0f / TT);
  for (int i = j; i < TDA_F; i += HH) x[i] = tda[b * TDA_F + i];
  __syncthreads();
  if (j < 64) {
    float acc = b1[j];
    const float* wr = W1 + j * TDA_F;
#pragma unroll 5
    for (int i = 0; i < TDA_F; ++i) acc = fmaf(x[i], wr[i], acc);
    h1[j] = fmaxf(acc, 0.0f);
  }
  __syncthreads();
  if (j < 64) {
    float acc = b2[j];
    const float* wr = W2 + j * 64;
#pragma unroll
    for (int i = 0; i < 64; ++i) acc = fmaf(h1[i], wr[i], acc);
    f[HH + j] = fmaxf(acc, 0.0f);
  }
  __syncthreads();
  float acc = bc1[j];
  const float* wr = Wc1 + j * (HH + 64);
#pragma unroll 4
  for (int i = 0; i < HH + 64; ++i) acc = fmaf(f[i], wr[i], acc);
  hbuf[b * HH + j] = acc;
}

// ---------------------------------------------------------------------------
// BN batch stats. R5: parallelized -- was 1 block x 128 threads scanning
// 256KB serially (single-CU, cross-XCD latency-bound). Now 128 blocks (one
// per column) x 256 threads; per-thread 2 strided loads, shuffle reduce.
// Reduction-order change perturbs mean/var only at ~1e-7.
// ---------------------------------------------------------------------------
__global__ __launch_bounds__(256) void bn_stats(
    const float* __restrict__ hbuf, float* __restrict__ stats /* [2*128] */)
{
  const int j = blockIdx.x;    // column
  const int t = threadIdx.x;   // 0..255
  float v0 = hbuf[(size_t)t * HH + j];
  float v1 = hbuf[(size_t)(t + 256) * HH + j];
  float s = v0 + v1;
  float qd = v0 * v0 + v1 * v1;
#pragma unroll
  for (int o = 32; o >= 1; o >>= 1) {
    s += __shfl_down(s, o);
    qd += __shfl_down(qd, o);
  }
  __shared__ float ps[4], pq[4];
  if ((t & 63) == 0) { ps[t >> 6] = s; pq[t >> 6] = qd; }
  __syncthreads();
  if (t == 0) {
    const float S = (ps[0] + ps[1]) + (ps[2] + ps[3]);
    const float Q = (pq[0] + pq[1]) + (pq[2] + pq[3]);
    const float mean = S * (1.0f / BB);
    const float var = Q * (1.0f / BB) - mean * mean;
    stats[j] = mean;
    stats[HH + j] = rsqrtf(var + EPSV);
  }
}

// ---------------------------------------------------------------------------
// BN apply + relu + 128->4 GEMM.
// ---------------------------------------------------------------------------
__global__ __launch_bounds__(HH) void classifier2(
    const float* __restrict__ hbuf, const float* __restrict__ stats,
    const float* __restrict__ gamma, const float* __restrict__ beta,
    const float* __restrict__ Wc2, const float* __restrict__ bc2,
    float* __restrict__ out)
{
  const int b = blockIdx.x, j = threadIdx.x;
  float hn = (hbuf[b * HH + j] - stats[j]) * stats[HH + j] * gamma[j] + beta[j];
  hn = fmaxf(hn, 0.0f);

  __shared__ float red[NCLS][HH];
#pragma unroll
  for (int k = 0; k < NCLS; ++k) red[k][j] = hn * Wc2[k * HH + j];
  __syncthreads();
  for (int off = HH / 2; off >= 1; off >>= 1) {
    if (j < off) {
#pragma unroll
      for (int k = 0; k < NCLS; ++k) red[k][j] += red[k][j + off];
    }
    __syncthreads();
  }
  if (j < NCLS) out[b * NCLS + j] = red[j][0] + bc2[j];
}

// ---------------------------------------------------------------------------
extern "C" void kernel_launch(void* const* d_in, const int* in_sizes, int n_in,
                              void* d_out, int out_size, void* d_ws, size_t ws_size,
                              hipStream_t stream)
{
  const float* kin  = (const float*)d_in[0];   // [512,1000,64]
  const float* tda  = (const float*)d_in[1];   // [512,150]
  const float* Wfc  = (const float*)d_in[2];   // [128,64]
  const float* bfc  = (const float*)d_in[3];   // [128]
  const float* Wt1  = (const float*)d_in[4];   // [64,150]
  const float* bt1  = (const float*)d_in[5];   // [64]
  const float* Wt2  = (const float*)d_in[6];   // [64,64]
  const float* bt2  = (const float*)d_in[7];   // [64]
  const float* Wc1  = (const float*)d_in[8];   // [128,192]
  const float* bc1  = (const float*)d_in[9];   // [128]
  const float* gam  = (const float*)d_in[10];  // [128]
  const float* bet  = (const float*)d_in[11];  // [128]
  const float* Wc2  = (const float*)d_in[12];  // [4,128]
  const float* bc2  = (const float*)d_in[13];  // [4]

  float* out    = (float*)d_out;        // output 0: [512,4]
  float* counts = out + BB * NCLS;      // output 1: [512,128]

  float* part  = (float*)d_ws;               // [8][512][128]  (2 MB)
  float* hbuf  = part + NSEG * BB * HH;      // [512,128]
  float* stats = hbuf + BB * HH;             // [256]

  snn_scan<<<BB * NSEG, 64, 0, stream>>>(kin, Wfc, bfc, part);
  fused_head<<<BB, HH, 0, stream>>>(part, tda, Wt1, bt1, Wt2, bt2,
                                    Wc1, bc1, counts, hbuf);
  bn_stats<<<HH, 256, 0, stream>>>(hbuf, stats);
  classifier2<<<BB, HH, 0, stream>>>(hbuf, stats, gam, bet, Wc2, bc2, out);
}

// Round 3
// 260.316 us; speedup vs baseline: 1.0301x; 1.0220x over previous
//
#include <hip/hip_runtime.h>
#include <stdint.h>

#define BB 512
#define TT 1000
#define CC 64
#define HH 128
#define TDA_F 150
#define NCLS 4
#define EPSV 1e-5f
#define NSEG 8
#define SEGLEN 125   // TT / NSEG
#define WARM 51      // uncounted warm-up; SEGLEN+WARM = 176 = 11 tiles of 16

typedef _Float16 half8 __attribute__((ext_vector_type(8)));
typedef float floatx4 __attribute__((ext_vector_type(4)));

// Split 8 fp32 values into fp16 hi + lo halves (hi = RTN cvt, lo = residual).
// (hi+lo) carries ~22 mantissa bits; 3-product MFMA error ~2^-21 relative.
__device__ __forceinline__ void split8(const float* v, half8& hi, half8& lo) {
#pragma unroll
  for (int i = 0; i < 8; ++i) {
    _Float16 h = (_Float16)v[i];
    hi[i] = h;
    lo[i] = (_Float16)(v[i] - (float)h);
  }
}

// ---------------------------------------------------------------------------
// Fused current-GEMM (split-fp16 MFMA) + LIF scan.
//
// R6/R7: OCCUPANCY, not pipelining. R5's in-wave software pipeline was
// measured neutral-to-negative (MfmaUtil 17.7->16.3): with only 2 waves/SIMD
// resident (124 VGPR + ~132 AGPR of weight frags ~= 250 of the 512-reg
// unified file), nothing hides latency. This version splits the h-dimension
// across 2 waves: grid 512b x 8seg x 2hh, each single-wave block owns 64 h
// (4 h-tiles). Weight frags halve to 64 regs, LIF state is 1 h/lane ->
// target <=128 unified regs = 4 waves/SIMD (launch_bounds(64,4)), and 8192
// waves of work (8/SIMD) instead of 4096 (4/SIMD). A-tile loads are
// duplicated across the hh-pair; kin (131 MB) is L3-resident so extra HBM
// fetch is small. Numerics bit-identical to R4/R5 (same MFMA order per h,
// same LIF order). Single cur buffer, no barriers (1-wave block; compiler
// orders DS ops via lgkmcnt). Pad 68: writes 2-way (free), reads 2-way.
// (R7 = R6 resubmitted verbatim: R6's bench died on container acquisition,
// an infra failure; no kernel-side cause found on audit.)
// ---------------------------------------------------------------------------
__global__ __launch_bounds__(64, 4) void snn_scan(
    const float* __restrict__ kin, const float* __restrict__ Wfc,
    const float* __restrict__ bfc, float* __restrict__ part)
{
  const int lane = threadIdx.x;
  const int q = lane >> 4;      // quad 0..3
  const int m = lane & 15;      // row-in-tile / col-in-tile index
  const int idx = blockIdx.x;
  const int hh = idx & 1;       // h-half: this wave owns h = hh*64 .. +63
  const int seg = (idx >> 1) & 7;
  const int b = idx >> 4;

  const int t0 = (seg == 0) ? 0 : SEGLEN * seg - WARM;
  const int ntiles = (seg == 0) ? 8 : 11;   // 128 or 176 steps
  const int lo = SEGLEN * seg;
  const int hi = lo + SEGLEN;

  // B fragments: B[n=m][k=q*8+j], n = hh*64 + ht*16 + m over 4 h-tiles,
  // k split in two 32-wide halves. 16 half8 frags = 64 regs.
  half8 bh[4][2], bl[4][2];
  float bv[4];
#pragma unroll
  for (int ht = 0; ht < 4; ++ht) {
    const int h = hh * 64 + ht * 16 + m;
    bv[ht] = bfc[h];
#pragma unroll
    for (int kh = 0; kh < 2; ++kh) {
      const float* wp = Wfc + h * CC + kh * 32 + q * 8;
      float av[8];
      float4 w0 = *(const float4*)(wp);
      float4 w1 = *(const float4*)(wp + 4);
      av[0] = w0.x; av[1] = w0.y; av[2] = w0.z; av[3] = w0.w;
      av[4] = w1.x; av[5] = w1.y; av[6] = w1.z; av[7] = w1.w;
      split8(av, bh[ht][kh], bl[ht][kh]);
    }
  }

  // Current tile: 16 t-rows x 64 h-cols, pad 68 (68%32=4 -> <=2-way banks
  // on both the write pattern and the cur[s][lane] read pattern).
  __shared__ float cur[16][68];

  // A pointer: lane reads rows t = t_base + m, cols q*8.. (two k-halves).
  const float* ab = kin + ((size_t)b * TT + (t0 + m)) * CC + q * 8;

  float4 p0 = *(const float4*)(ab);
  float4 p1 = *(const float4*)(ab + 4);
  float4 p2 = *(const float4*)(ab + 32);
  float4 p3 = *(const float4*)(ab + 36);

  float mem = 0.f, cnt = 0.f;

  for (int tile = 0; tile < ntiles; ++tile) {
    float4 c0 = p0, c1 = p1, c2 = p2, c3 = p3;
    if (tile + 1 < ntiles) {
      ab += 16 * CC;
      p0 = *(const float4*)(ab);
      p1 = *(const float4*)(ab + 4);
      p2 = *(const float4*)(ab + 32);
      p3 = *(const float4*)(ab + 36);
    }

    // A frags for the two k-halves.
    float av0[8] = {c0.x, c0.y, c0.z, c0.w, c1.x, c1.y, c1.z, c1.w};
    float av1[8] = {c2.x, c2.y, c2.z, c2.w, c3.x, c3.y, c3.z, c3.w};
    half8 ah0, al0, ah1, al1;
    split8(av0, ah0, al0);
    split8(av1, ah1, al1);

#pragma unroll
    for (int ht = 0; ht < 4; ++ht) {
      floatx4 acc = {bv[ht], bv[ht], bv[ht], bv[ht]};  // bias folded in
      acc = __builtin_amdgcn_mfma_f32_16x16x32_f16(al0, bh[ht][0], acc, 0, 0, 0);
      acc = __builtin_amdgcn_mfma_f32_16x16x32_f16(ah0, bl[ht][0], acc, 0, 0, 0);
      acc = __builtin_amdgcn_mfma_f32_16x16x32_f16(ah0, bh[ht][0], acc, 0, 0, 0);
      acc = __builtin_amdgcn_mfma_f32_16x16x32_f16(al1, bh[ht][1], acc, 0, 0, 0);
      acc = __builtin_amdgcn_mfma_f32_16x16x32_f16(ah1, bl[ht][1], acc, 0, 0, 0);
      acc = __builtin_amdgcn_mfma_f32_16x16x32_f16(ah1, bh[ht][1], acc, 0, 0, 0);
      // C/D layout: col = lane&15 (h within tile), row = q*4 + reg (t).
#pragma unroll
      for (int r = 0; r < 4; ++r) cur[q * 4 + r][ht * 16 + m] = acc[r];
    }

    // Serial LIF over the 16 steps; lane owns h = hh*64 + lane.
    const int tb = t0 + tile * 16;
#pragma unroll
    for (int s = 0; s < 16; ++s) {
      const float cu = cur[s][lane];
      const int t = tb + s;
      const bool act = (t >= lo) && (t < hi);  // wave-uniform
      mem = fmaf(0.9f, mem, cu);
      const bool sp = (mem >= 1.0f);
      cnt += (act && sp) ? 1.0f : 0.0f;
      mem = sp ? 0.0f : mem;
    }
  }

  part[((size_t)(seg * BB + b)) * HH + hh * 64 + lane] = cnt;
}

// ---------------------------------------------------------------------------
// Fused head: partial-count reduce + counts output + tda_net
// (150->64 relu ->64 relu) + fc1 (192->128). No atomics.
// ---------------------------------------------------------------------------
__global__ __launch_bounds__(HH) void fused_head(
    const float* __restrict__ part, const float* __restrict__ tda,
    const float* __restrict__ W1, const float* __restrict__ b1,
    const float* __restrict__ W2, const float* __restrict__ b2,
    const float* __restrict__ Wc1, const float* __restrict__ bc1,
    float* __restrict__ counts_out, float* __restrict__ hbuf)
{
  const int b = blockIdx.x, j = threadIdx.x;
  __shared__ float x[TDA_F];
  __shared__ float h1[64];
  __shared__ float f[HH + 64];

  float c = 0.0f;
#pragma unroll
  for (int s = 0; s < NSEG; ++s) c += part[((size_t)(s * BB + b)) * HH + j];
  counts_out[b * HH + j] = c;
  f[j] = c * (1.0f / TT);
  for (int i = j; i < TDA_F; i += HH) x[i] = tda[b * TDA_F + i];
  __syncthreads();
  if (j < 64) {
    float acc = b1[j];
    const float* wr = W1 + j * TDA_F;
#pragma unroll 5
    for (int i = 0; i < TDA_F; ++i) acc = fmaf(x[i], wr[i], acc);
    h1[j] = fmaxf(acc, 0.0f);
  }
  __syncthreads();
  if (j < 64) {
    float acc = b2[j];
    const float* wr = W2 + j * 64;
#pragma unroll
    for (int i = 0; i < 64; ++i) acc = fmaf(h1[i], wr[i], acc);
    f[HH + j] = fmaxf(acc, 0.0f);
  }
  __syncthreads();
  float acc = bc1[j];
  const float* wr = Wc1 + j * (HH + 64);
#pragma unroll 4
  for (int i = 0; i < HH + 64; ++i) acc = fmaf(f[i], wr[i], acc);
  hbuf[b * HH + j] = acc;
}

// ---------------------------------------------------------------------------
// BN batch stats: 128 blocks (one per column) x 256 threads; per-thread 2
// strided loads, shuffle reduce. Reduction-order perturbs mean/var ~1e-7.
// ---------------------------------------------------------------------------
__global__ __launch_bounds__(256) void bn_stats(
    const float* __restrict__ hbuf, float* __restrict__ stats /* [2*128] */)
{
  const int j = blockIdx.x;    // column
  const int t = threadIdx.x;   // 0..255
  float v0 = hbuf[(size_t)t * HH + j];
  float v1 = hbuf[(size_t)(t + 256) * HH + j];
  float s = v0 + v1;
  float qd = v0 * v0 + v1 * v1;
#pragma unroll
  for (int o = 32; o >= 1; o >>= 1) {
    s += __shfl_down(s, o);
    qd += __shfl_down(qd, o);
  }
  __shared__ float ps[4], pq[4];
  if ((t & 63) == 0) { ps[t >> 6] = s; pq[t >> 6] = qd; }
  __syncthreads();
  if (t == 0) {
    const float S = (ps[0] + ps[1]) + (ps[2] + ps[3]);
    const float Q = (pq[0] + pq[1]) + (pq[2] + pq[3]);
    const float mean = S * (1.0f / BB);
    const float var = Q * (1.0f / BB) - mean * mean;
    stats[j] = mean;
    stats[HH + j] = rsqrtf(var + EPSV);
  }
}

// ---------------------------------------------------------------------------
// BN apply + relu + 128->4 GEMM.
// ---------------------------------------------------------------------------
__global__ __launch_bounds__(HH) void classifier2(
    const float* __restrict__ hbuf, const float* __restrict__ stats,
    const float* __restrict__ gamma, const float* __restrict__ beta,
    const float* __restrict__ Wc2, const float* __restrict__ bc2,
    float* __restrict__ out)
{
  const int b = blockIdx.x, j = threadIdx.x;
  float hn = (hbuf[b * HH + j] - stats[j]) * stats[HH + j] * gamma[j] + beta[j];
  hn = fmaxf(hn, 0.0f);

  __shared__ float red[NCLS][HH];
#pragma unroll
  for (int k = 0; k < NCLS; ++k) red[k][j] = hn * Wc2[k * HH + j];
  __syncthreads();
  for (int off = HH / 2; off >= 1; off >>= 1) {
    if (j < off) {
#pragma unroll
      for (int k = 0; k < NCLS; ++k) red[k][j] += red[k][j + off];
    }
    __syncthreads();
  }
  if (j < NCLS) out[b * NCLS + j] = red[j][0] + bc2[j];
}

// ---------------------------------------------------------------------------
extern "C" void kernel_launch(void* const* d_in, const int* in_sizes, int n_in,
                              void* d_out, int out_size, void* d_ws, size_t ws_size,
                              hipStream_t stream)
{
  const float* kin  = (const float*)d_in[0];   // [512,1000,64]
  const float* tda  = (const float*)d_in[1];   // [512,150]
  const float* Wfc  = (const float*)d_in[2];   // [128,64]
  const float* bfc  = (const float*)d_in[3];   // [128]
  const float* Wt1  = (const float*)d_in[4];   // [64,150]
  const float* bt1  = (const float*)d_in[5];   // [64]
  const float* Wt2  = (const float*)d_in[6];   // [64,64]
  const float* bt2  = (const float*)d_in[7];   // [64]
  const float* Wc1  = (const float*)d_in[8];   // [128,192]
  const float* bc1  = (const float*)d_in[9];   // [128]
  const float* gam  = (const float*)d_in[10];  // [128]
  const float* bet  = (const float*)d_in[11];  // [128]
  const float* Wc2  = (const float*)d_in[12];  // [4,128]
  const float* bc2  = (const float*)d_in[13];  // [4]

  float* out    = (float*)d_out;        // output 0: [512,4]
  float* counts = out + BB * NCLS;      // output 1: [512,128]

  float* part  = (float*)d_ws;               // [8][512][128]  (2 MB)
  float* hbuf  = part + NSEG * BB * HH;      // [512,128]
  float* stats = hbuf + BB * HH;             // [256]

  snn_scan<<<BB * NSEG * 2, 64, 0, stream>>>(kin, Wfc, bfc, part);
  fused_head<<<BB, HH, 0, stream>>>(part, tda, Wt1, bt1, Wt2, bt2,
                                    Wc1, bc1, counts, hbuf);
  bn_stats<<<HH, 256, 0, stream>>>(hbuf, stats);
  classifier2<<<BB, HH, 0, stream>>>(hbuf, stats, gam, bet, Wc2, bc2, out);
}